// Round 11
// baseline (111.268 us; speedup 1.0000x reference)
//
#include <hip/hip_runtime.h>
#include <hip/hip_bf16.h>

#define HH 128
#define WW 128
#define CI 64
#define CO 64
#define SLS 584    // LDS row stride in bf16 elems (576 + 8 pad)
#define A_HPS 72   // halo shorts per pixel (64 ch + 8 pad)
#define A_HW 66    // halo width: image cols w0-1 .. w0+64

typedef __attribute__((ext_vector_type(8))) short short8;
typedef __attribute__((ext_vector_type(4))) float floatx4;

__device__ __forceinline__ unsigned short f2bf(float f) {
  union { float f; unsigned u; } uu; uu.f = f;
  unsigned r = uu.u + 0x7FFFu + ((uu.u >> 16) & 1u);  // RNE
  return (unsigned short)(r >> 16);
}
__device__ __forceinline__ unsigned pack2bf(float lo, float hi) {
  return (unsigned)f2bf(lo) | ((unsigned)f2bf(hi) << 16);
}

// ---- offA: per (b,h,half-row). Stages w_off->LDS (transposed bf16) per block,
//      3-row/66-col x halo, emits xTb row, offset GEMM -> om32.
//      Blocks 0..143 additionally write Wm/bias2 for dcnB (one elem/thread).
// 512 blocks (2/CU), 256 threads = 4 waves.
__global__ __launch_bounds__(256) void offA_kernel(
    const float* __restrict__ x, unsigned* __restrict__ xTb_u,
    const float* __restrict__ w_off, const float* __restrict__ b_off,
    const float* __restrict__ weight, const float* __restrict__ bias,
    const float* __restrict__ gamma, const float* __restrict__ beta,
    const float* __restrict__ mean, const float* __restrict__ var,
    unsigned short* __restrict__ Wm, float* __restrict__ bias2,
    float* __restrict__ om32) {
  __shared__ short halo[3 * A_HW * A_HPS];  // 28,512 B, zero-padded
  __shared__ short w2L[32 * 576];           // 36,864 B (total 65,376 <= 64 KiB)
  int bid = blockIdx.x;
  int s = bid & 7;              // XCD slab key
  int n = bid >> 3;             // 0..63
  int b = n >> 5;
  int rest = n & 31;
  int h = s * 16 + (rest & 15);
  int w0 = (rest >> 4) * 64;
  int tid = threadIdx.x;

  // prep for dcnB (blocks 0..143): Wm[o][k*64+c] = weight*inv, bias2
  if (bid < 144) {
    int idx = bid * 256 + tid;            // exactly covers 64*576 = 36,864
    int o = ((idx >> 6) * 7282) >> 16;    // idx/576  (idx>>6 < 576, magic ok)
    int kc = idx - o * 576;
    int k = kc >> 6, c = kc & 63;
    float inv = gamma[o] * rsqrtf(var[o] + 1e-5f);
    Wm[idx] = f2bf(weight[(o * CI + c) * 9 + k] * inv);
    if (kc == 0) bias2[o] = (bias[o] - mean[o]) * inv + beta[o];
  }

  // stage w2L: linear read of w_off (27*576 fp32), transposed scatter to LDS
  for (int i = tid; i < 27 * 576; i += 256) {
    float v = w_off[i];
    int o = ((i >> 6) * 7282) >> 16;      // i/576 (i>>6 < 243)
    int rem = i - o * 576;
    int c = (rem * 7282) >> 16;           // rem/9 (rem < 576)
    int k = rem - c * 9;
    w2L[o * 576 + k * 64 + c] = (short)f2bf(v);
  }
  for (int j = tid; j < 1440; j += 256)   // zero rows 27..31 (5*576 shorts)
    ((unsigned*)&w2L[27 * 576])[j] = 0u;

  // stage halo: 792 tasks = 3 rows x 66 px x 4 cgroups(16 ch); zeros out-of-image
#pragma unroll
  for (int it = 0; it < 4; it++) {
    int t = it * 256 + tid;
    if (t < 792) {
      int row = t / 264;
      int r2 = t - row * 264;
      int cg4 = r2 / 66;
      int px = r2 - cg4 * 66;
      int y = h - 1 + row;
      int xi = w0 - 1 + px;
      int c0 = cg4 * 16;
      float f[16];
      if (((unsigned)y < (unsigned)HH) && ((unsigned)xi < (unsigned)WW)) {
        const float* xp = x + ((long)(b * CI + c0) * HH + y) * WW + xi;
#pragma unroll
        for (int q = 0; q < 16; q++) f[q] = xp[q * (HH * WW)];
      } else {
#pragma unroll
        for (int q = 0; q < 16; q++) f[q] = 0.f;
      }
      short* hp = &halo[(row * A_HW + px) * A_HPS + c0];
#pragma unroll
      for (int q = 0; q < 4; q++)  // uint2 = 4 shorts
        *(uint2*)(hp + q * 4) =
            make_uint2(pack2bf(f[4 * q], f[4 * q + 1]), pack2bf(f[4 * q + 2], f[4 * q + 3]));
    }
  }
  __syncthreads();  // halo + w2L ready

  // emit xTb for this block's 64 px (bf16 NHWC pairs, coalesced)
  {
    int cp = tid & 31;
    int pw = tid >> 5;
#pragma unroll
    for (int it = 0; it < 8; it++) {
      int px = it * 8 + pw;
      unsigned u = *(const unsigned*)&halo[(A_HW + px + 1) * A_HPS + 2 * cp];
      xTb_u[((b * HH + h) * WW + w0 + px) * 32 + cp] = u;
    }
  }

  // offset GEMM: M=32 (2 m-tiles), N=64 (4 n-tiles), K=576; A from w2L (LDS)
  int lane = tid & 63, wave = tid >> 6;
  int r16 = lane & 15, quad = lane >> 4;
  int m16 = wave & 1;
  floatx4 binit;
#pragma unroll
  for (int r = 0; r < 4; r++) {
    int oc = m16 * 16 + quad * 4 + r;
    binit[r] = (oc < 27) ? b_off[oc] : 0.f;
  }
  const short* ap = &w2L[(m16 * 16 + r16) * 576];
#pragma unroll
  for (int i = 0; i < 2; i++) {
    int nt = (wave >> 1) + 2 * i;
    floatx4 t = binit;
#pragma unroll
    for (int kk = 0; kk < 9; kk++) {
      int dy = kk / 3, dx = kk - 3 * (kk / 3);
      const short* hp = &halo[(dy * A_HW + nt * 16 + r16 + dx) * A_HPS];
      short8 b0 = *(const short8*)(hp + quad * 8);
      short8 b1 = *(const short8*)(hp + 32 + quad * 8);
      short8 a0 = *(const short8*)(ap + kk * 64 + quad * 8);
      short8 a1 = *(const short8*)(ap + kk * 64 + 32 + quad * 8);
      t = __builtin_amdgcn_mfma_f32_16x16x32_bf16(a0, b0, t, 0, 0, 0);
      t = __builtin_amdgcn_mfma_f32_16x16x32_bf16(a1, b1, t, 0, 0, 0);
    }
    float* orow = om32 + (long)((b * HH + h) * WW + w0 + nt * 16 + r16) * 32;
#pragma unroll
    for (int r = 0; r < 4; r++) {
      int oc = m16 * 16 + quad * 4 + r;
      if (oc < 27) orow[oc] = t[r];
    }
  }
}

// ---- dcnB: 16 px/block, 2048 blocks. params -> b32 gathers -> 1 barrier -> GEMM ----
// (byte-identical to round-8 best-measured version)
__global__ __launch_bounds__(256) void dcnB_kernel(
    const unsigned short* __restrict__ xTb, const float* __restrict__ om32,
    const unsigned short* __restrict__ Wm, const float* __restrict__ bias2,
    float* __restrict__ out) {
  __shared__ __hip_bfloat16 SL[16 * SLS];  // 18,688 B
  __shared__ float4 Pw[144];               //  2,304 B
  __shared__ int2 Po[144];                 //  1,152 B (off00, dx|dy<<16)

  int bid = blockIdx.x;
  int s = bid & 7;
  int n = bid >> 3;             // 0..255
  int b = n >> 7;
  int rem = n & 127;
  int h = s * 16 + (rem >> 3);
  int w0 = (rem & 7) * 16;

  int tid = threadIdx.x, lane = tid & 63, wave = tid >> 6;
  const unsigned short* xb = xTb + b * (HH * WW * CI);
  int rowpix = (b * HH + h) * WW + w0;

  // params: 36 (p,k) tasks per wave for its 4 pixels (intra-wave only)
  if (lane < 36) {
    int p_loc = (lane * 7282) >> 16;  // lane/9
    int k = lane - p_loc * 9;
    int p = wave * 4 + p_loc;
    const float* ob = om32 + (long)(rowpix + p) * 32;
    float oy = ob[2 * k], ox = ob[2 * k + 1], mm = ob[18 + k];
    float msk = 1.f / (1.f + __expf(-mm));
    int ky = (k * 11) >> 5;  // k/3
    int kx = k - 3 * ky;
    float py = (float)(h - 1 + ky) + oy;
    float px = (float)(w0 + p - 1 + kx) + ox;
    float y0f = floorf(py), x0f = floorf(px);
    float ly = py - y0f, lx = px - x0f;
    int y0 = (int)y0f, x0 = (int)x0f;
    int y1 = y0 + 1, x1 = x0 + 1;
    float lylx = ly * lx;
    bool y0v = (unsigned)y0 < (unsigned)HH, y1v = (unsigned)y1 < (unsigned)HH;
    bool x0v = (unsigned)x0 < (unsigned)WW, x1v = (unsigned)x1 < (unsigned)WW;
    int yc0 = min(max(y0, 0), HH - 1), yc1 = min(max(y1, 0), HH - 1);
    int xc0 = min(max(x0, 0), WW - 1), xc1 = min(max(x1, 0), WW - 1);
    Pw[p * 9 + k] = make_float4((y0v && x0v) ? (1.f - ly - lx + lylx) * msk : 0.f,
                                (y0v && x1v) ? (lx - lylx) * msk : 0.f,
                                (y1v && x0v) ? (ly - lylx) * msk : 0.f,
                                (y1v && x1v) ? lylx * msk : 0.f);
    int dxs = (xc1 - xc0) * CI;        // 0 or 64
    int dys = (yc1 - yc0) * WW * CI;   // 0 or 8192
    Po[p * 9 + k] = make_int2((yc0 * WW + xc0) * CI, dxs | (dys << 16));
  }

  // gather: 2 px per half-wave, 72 independent b32 global loads per thread
  int cp = lane & 31, ph = lane >> 5, ch = 2 * cp;
#pragma unroll
  for (int j = 0; j < 2; j++) {
    int p = wave * 4 + j * 2 + ph;
#pragma unroll
    for (int k = 0; k < 9; k++) {
      float4 wv = Pw[p * 9 + k];
      int2 po = Po[p * 9 + k];
      int o00 = po.x + ch;
      int dx = po.y & 0xffff;
      int dyv = po.y >> 16;
      unsigned u00 = *(const unsigned*)(xb + o00);
      unsigned u01 = *(const unsigned*)(xb + o00 + dx);
      unsigned u10 = *(const unsigned*)(xb + o00 + dyv);
      unsigned u11 = *(const unsigned*)(xb + o00 + dyv + dx);
      float lo = __uint_as_float(u00 << 16) * wv.x + __uint_as_float(u01 << 16) * wv.y +
                 __uint_as_float(u10 << 16) * wv.z + __uint_as_float(u11 << 16) * wv.w;
      float hi = __uint_as_float(u00 & 0xffff0000u) * wv.x + __uint_as_float(u01 & 0xffff0000u) * wv.y +
                 __uint_as_float(u10 & 0xffff0000u) * wv.z + __uint_as_float(u11 & 0xffff0000u) * wv.w;
      *(unsigned*)(&SL[p * SLS + k * 64 + ch]) = pack2bf(lo, hi);
    }
  }
  __syncthreads();  // the one barrier: SL complete

  // main GEMM: wave's 16 o x block's 16 px, K=576; BN bias in C-init, ReLU
  int r16 = lane & 15, quad = lane >> 4;
  floatx4 acc = *(const floatx4*)(bias2 + wave * 16 + quad * 4);
  const unsigned short* Ap = Wm + (wave * 16 + r16) * 576 + quad * 8;
  const __hip_bfloat16* Sp = &SL[r16 * SLS + quad * 8];
#pragma unroll
  for (int kc0 = 0; kc0 < 576; kc0 += 32) {
    short8 av = *(const short8*)(Ap + kc0);
    short8 bv = *(const short8*)(Sp + kc0);
    acc = __builtin_amdgcn_mfma_f32_16x16x32_bf16(av, bv, acc, 0, 0, 0);
  }
#pragma unroll
  for (int r = 0; r < 4; r++) {
    int o = wave * 16 + quad * 4 + r;
    out[((b * CO + o) * HH + h) * WW + w0 + r16] = fmaxf(acc[r], 0.f);
  }
}

extern "C" void kernel_launch(void* const* d_in, const int* in_sizes, int n_in,
                              void* d_out, int out_size, void* d_ws, size_t ws_size,
                              hipStream_t stream) {
  const float* x = (const float*)d_in[0];
  const float* w_off = (const float*)d_in[1];
  const float* b_off = (const float*)d_in[2];
  const float* weight = (const float*)d_in[3];
  const float* bias = (const float*)d_in[4];
  const float* gamma = (const float*)d_in[5];
  const float* beta = (const float*)d_in[6];
  const float* run_mean = (const float*)d_in[7];
  const float* run_var = (const float*)d_in[8];
  float* outp = (float*)d_out;

  char* ws = (char*)d_ws;
  unsigned* xTb = (unsigned*)ws;                           //  4,194,304 B (bf16 NHWC)
  float* om32 = (float*)(ws + 4194304);                    //  4,194,304 B
  unsigned short* Wm = (unsigned short*)(ws + 8388608);    //     73,728 B
  float* bias2 = (float*)(ws + 8462336);                   //        256 B

  offA_kernel<<<512, 256, 0, stream>>>(x, xTb, w_off, b_off, weight, bias,
                                       gamma, beta, run_mean, run_var,
                                       Wm, bias2, om32);
  dcnB_kernel<<<2048, 256, 0, stream>>>((const unsigned short*)xTb, om32, Wm, bias2, outp);
}

// Round 12
// 109.979 us; speedup vs baseline: 1.0117x; 1.0117x over previous
//
#include <hip/hip_runtime.h>
#include <hip/hip_bf16.h>

#define HH 128
#define WW 128
#define CI 64
#define CO 64
#define SLS 584    // LDS row stride in bf16 elems (576 + 8 pad)
#define A_HPS 72   // halo shorts per pixel (64 ch + 8 pad, 144B = 9x16B aligned)
#define A_HW 66    // halo width: image cols w0-1 .. w0+64

typedef __attribute__((ext_vector_type(8))) short short8;
typedef __attribute__((ext_vector_type(4))) float floatx4;

__device__ __forceinline__ unsigned short f2bf(float f) {
  union { float f; unsigned u; } uu; uu.f = f;
  unsigned r = uu.u + 0x7FFFu + ((uu.u >> 16) & 1u);  // RNE
  return (unsigned short)(r >> 16);
}
__device__ __forceinline__ unsigned pack2bf(float lo, float hi) {
  return (unsigned)f2bf(lo) | ((unsigned)f2bf(hi) << 16);
}

// ---- prep: Wm[o][k*64+c]=weight*inv (bf16 64x576); w2[32][576]; bias2; boff2 ----
__global__ __launch_bounds__(256) void prep_kernel(
    const float* __restrict__ weight, const float* __restrict__ bias,
    const float* __restrict__ gamma, const float* __restrict__ beta,
    const float* __restrict__ mean, const float* __restrict__ var,
    const float* __restrict__ w_off, const float* __restrict__ b_off,
    unsigned short* __restrict__ Wm, unsigned short* __restrict__ w2,
    float* __restrict__ bias2, float* __restrict__ boff2) {
  int idx = blockIdx.x * 256 + threadIdx.x;
  if (idx < 32) boff2[idx] = (idx < 27) ? b_off[idx] : 0.f;
  if (idx >= CO * 576) return;
  int o = idx / 576, kc = idx - o * 576;
  int k = kc >> 6, c = kc & 63;
  float inv = gamma[o] * rsqrtf(var[o] + 1e-5f);
  Wm[idx] = f2bf(weight[(o * CI + c) * 9 + k] * inv);
  if (kc == 0) bias2[o] = (bias[o] - mean[o]) * inv + beta[o];
  if (o < 27) w2[idx] = f2bf(w_off[o * 576 + c * 9 + k]);
  else if (o < 32) w2[idx] = 0;
}

// ---- offA: per (b,h,half-row) — 3-row/66-col bf16 halo, emit xTb, offset GEMM ----
// 512 blocks (2/CU), 256 threads = 4 waves.
__global__ __launch_bounds__(256) void offA_kernel(
    const float* __restrict__ x, unsigned* __restrict__ xTb_u,
    const unsigned short* __restrict__ w2, const float* __restrict__ boff2,
    float* __restrict__ om32) {
  __shared__ short halo[3 * A_HW * A_HPS];  // 28,512 B, zero-padded
  int bid = blockIdx.x;
  int s = bid & 7;              // XCD slab key
  int n = bid >> 3;             // 0..63
  int b = n >> 5;
  int rest = n & 31;
  int h = s * 16 + (rest & 15);
  int w0 = (rest >> 4) * 64;
  int tid = threadIdx.x;

  // stage: 792 tasks = 3 rows x 66 px x 4 cgroups(16 ch); zeros for out-of-image
#pragma unroll
  for (int it = 0; it < 4; it++) {
    int t = it * 256 + tid;
    if (t < 792) {
      int row = t / 264;
      int r2 = t - row * 264;
      int cg4 = r2 / 66;
      int px = r2 - cg4 * 66;
      int y = h - 1 + row;
      int xi = w0 - 1 + px;
      int c0 = cg4 * 16;
      float f[16];
      if (((unsigned)y < (unsigned)HH) && ((unsigned)xi < (unsigned)WW)) {
        const float* xp = x + ((long)(b * CI + c0) * HH + y) * WW + xi;
#pragma unroll
        for (int q = 0; q < 16; q++) f[q] = xp[q * (HH * WW)];
      } else {
#pragma unroll
        for (int q = 0; q < 16; q++) f[q] = 0.f;
      }
      short* hp = &halo[(row * A_HW + px) * A_HPS + c0];
#pragma unroll
      for (int q = 0; q < 4; q++)  // uint2 = 4 shorts
        *(uint2*)(hp + q * 4) =
            make_uint2(pack2bf(f[4 * q], f[4 * q + 1]), pack2bf(f[4 * q + 2], f[4 * q + 3]));
    }
  }
  __syncthreads();

  // emit xTb for this block's 64 px (bf16 NHWC pairs, coalesced)
  {
    int cp = tid & 31;
    int pw = tid >> 5;
#pragma unroll
    for (int it = 0; it < 8; it++) {
      int px = it * 8 + pw;
      unsigned u = *(const unsigned*)&halo[(A_HW + px + 1) * A_HPS + 2 * cp];
      xTb_u[((b * HH + h) * WW + w0 + px) * 32 + cp] = u;
    }
  }

  // offset GEMM: M=32 (2 m-tiles), N=64 (4 n-tiles), K=576
  int lane = tid & 63, wave = tid >> 6;
  int r16 = lane & 15, quad = lane >> 4;
  int m16 = wave & 1;
  floatx4 binit = *(const floatx4*)(boff2 + m16 * 16 + quad * 4);
  const short* ap = (const short*)(w2 + (m16 * 16 + r16) * 576);
#pragma unroll
  for (int i = 0; i < 2; i++) {
    int nt = (wave >> 1) + 2 * i;
    floatx4 t = binit;
#pragma unroll
    for (int kk = 0; kk < 9; kk++) {
      int dy = kk / 3, dx = kk - 3 * (kk / 3);
      const short* hp = &halo[(dy * A_HW + nt * 16 + r16 + dx) * A_HPS];
      short8 b0 = *(const short8*)(hp + quad * 8);
      short8 b1 = *(const short8*)(hp + 32 + quad * 8);
      short8 a0 = *(const short8*)(ap + kk * 64 + quad * 8);
      short8 a1 = *(const short8*)(ap + kk * 64 + 32 + quad * 8);
      t = __builtin_amdgcn_mfma_f32_16x16x32_bf16(a0, b0, t, 0, 0, 0);
      t = __builtin_amdgcn_mfma_f32_16x16x32_bf16(a1, b1, t, 0, 0, 0);
    }
    float* orow = om32 + (long)((b * HH + h) * WW + w0 + nt * 16 + r16) * 32;
#pragma unroll
    for (int r = 0; r < 4; r++) {
      int oc = m16 * 16 + quad * 4 + r;
      if (oc < 27) orow[oc] = t[r];
    }
  }
}

// ---- dcnB: 16 px/block, 2048 blocks. params -> gathers -> 1 barrier -> GEMM ----
__global__ __launch_bounds__(256) void dcnB_kernel(
    const unsigned short* __restrict__ xTb, const float* __restrict__ om32,
    const unsigned short* __restrict__ Wm, const float* __restrict__ bias2,
    float* __restrict__ out) {
  __shared__ __hip_bfloat16 SL[16 * SLS];  // 18,688 B
  __shared__ float4 Pw[144];               //  2,304 B
  __shared__ int2 Po[144];                 //  1,152 B (off00, dx|dy<<16)

  int bid = blockIdx.x;
  int s = bid & 7;
  int n = bid >> 3;             // 0..255
  int b = n >> 7;
  int rem = n & 127;
  int h = s * 16 + (rem >> 3);
  int w0 = (rem & 7) * 16;

  int tid = threadIdx.x, lane = tid & 63, wave = tid >> 6;
  const unsigned short* xb = xTb + b * (HH * WW * CI);
  int rowpix = (b * HH + h) * WW + w0;

  // params: 36 (p,k) tasks per wave for its 4 pixels (intra-wave only)
  if (lane < 36) {
    int p_loc = (lane * 7282) >> 16;  // lane/9
    int k = lane - p_loc * 9;
    int p = wave * 4 + p_loc;
    const float* ob = om32 + (long)(rowpix + p) * 32;
    float oy = ob[2 * k], ox = ob[2 * k + 1], mm = ob[18 + k];
    float msk = 1.f / (1.f + __expf(-mm));
    int ky = (k * 11) >> 5;  // k/3
    int kx = k - 3 * ky;
    float py = (float)(h - 1 + ky) + oy;
    float px = (float)(w0 + p - 1 + kx) + ox;
    float y0f = floorf(py), x0f = floorf(px);
    float ly = py - y0f, lx = px - x0f;
    int y0 = (int)y0f, x0 = (int)x0f;
    int y1 = y0 + 1, x1 = x0 + 1;
    float lylx = ly * lx;
    bool y0v = (unsigned)y0 < (unsigned)HH, y1v = (unsigned)y1 < (unsigned)HH;
    bool x0v = (unsigned)x0 < (unsigned)WW, x1v = (unsigned)x1 < (unsigned)WW;
    int yc0 = min(max(y0, 0), HH - 1), yc1 = min(max(y1, 0), HH - 1);
    int xc0 = min(max(x0, 0), WW - 1), xc1 = min(max(x1, 0), WW - 1);
    Pw[p * 9 + k] = make_float4((y0v && x0v) ? (1.f - ly - lx + lylx) * msk : 0.f,
                                (y0v && x1v) ? (lx - lylx) * msk : 0.f,
                                (y1v && x0v) ? (ly - lylx) * msk : 0.f,
                                (y1v && x1v) ? lylx * msk : 0.f);
    int dxs = (xc1 - xc0) * CI;        // 0 or 64
    int dys = (yc1 - yc0) * WW * CI;   // 0 or 8192
    Po[p * 9 + k] = make_int2((yc0 * WW + xc0) * CI, dxs | (dys << 16));
  }

  // gather: 2 px per half-wave, 72 independent b32 global loads per thread
  int cp = lane & 31, ph = lane >> 5, ch = 2 * cp;
#pragma unroll
  for (int j = 0; j < 2; j++) {
    int p = wave * 4 + j * 2 + ph;
#pragma unroll
    for (int k = 0; k < 9; k++) {
      float4 wv = Pw[p * 9 + k];
      int2 po = Po[p * 9 + k];
      int o00 = po.x + ch;
      int dx = po.y & 0xffff;
      int dyv = po.y >> 16;
      unsigned u00 = *(const unsigned*)(xb + o00);
      unsigned u01 = *(const unsigned*)(xb + o00 + dx);
      unsigned u10 = *(const unsigned*)(xb + o00 + dyv);
      unsigned u11 = *(const unsigned*)(xb + o00 + dyv + dx);
      float lo = __uint_as_float(u00 << 16) * wv.x + __uint_as_float(u01 << 16) * wv.y +
                 __uint_as_float(u10 << 16) * wv.z + __uint_as_float(u11 << 16) * wv.w;
      float hi = __uint_as_float(u00 & 0xffff0000u) * wv.x + __uint_as_float(u01 & 0xffff0000u) * wv.y +
                 __uint_as_float(u10 & 0xffff0000u) * wv.z + __uint_as_float(u11 & 0xffff0000u) * wv.w;
      *(unsigned*)(&SL[p * SLS + k * 64 + ch]) = pack2bf(lo, hi);
    }
  }
  __syncthreads();  // the one barrier: SL complete

  // main GEMM: wave's 16 o x block's 16 px, K=576; BN bias in C-init, ReLU
  int r16 = lane & 15, quad = lane >> 4;
  floatx4 acc = *(const floatx4*)(bias2 + wave * 16 + quad * 4);
  const unsigned short* Ap = Wm + (wave * 16 + r16) * 576 + quad * 8;
  const __hip_bfloat16* Sp = &SL[r16 * SLS + quad * 8];
#pragma unroll
  for (int kc0 = 0; kc0 < 576; kc0 += 32) {
    short8 av = *(const short8*)(Ap + kc0);
    short8 bv = *(const short8*)(Sp + kc0);
    acc = __builtin_amdgcn_mfma_f32_16x16x32_bf16(av, bv, acc, 0, 0, 0);
  }
#pragma unroll
  for (int r = 0; r < 4; r++) {
    int o = wave * 16 + quad * 4 + r;
    out[((b * CO + o) * HH + h) * WW + w0 + r16] = fmaxf(acc[r], 0.f);
  }
}

extern "C" void kernel_launch(void* const* d_in, const int* in_sizes, int n_in,
                              void* d_out, int out_size, void* d_ws, size_t ws_size,
                              hipStream_t stream) {
  const float* x = (const float*)d_in[0];
  const float* w_off = (const float*)d_in[1];
  const float* b_off = (const float*)d_in[2];
  const float* weight = (const float*)d_in[3];
  const float* bias = (const float*)d_in[4];
  const float* gamma = (const float*)d_in[5];
  const float* beta = (const float*)d_in[6];
  const float* run_mean = (const float*)d_in[7];
  const float* run_var = (const float*)d_in[8];
  float* outp = (float*)d_out;

  char* ws = (char*)d_ws;
  unsigned* xTb = (unsigned*)ws;                           //  4,194,304 B (bf16 NHWC)
  float* om32 = (float*)(ws + 4194304);                    //  4,194,304 B
  unsigned short* Wm = (unsigned short*)(ws + 8388608);    //     73,728 B
  unsigned short* w2 = (unsigned short*)(ws + 8462336);    //     36,864 B
  float* bias2 = (float*)(ws + 8499200);                   //        256 B
  float* boff2 = (float*)(ws + 8499456);                   //        128 B

  prep_kernel<<<144, 256, 0, stream>>>(weight, bias, gamma, beta, run_mean, run_var,
                                       w_off, b_off, Wm, w2, bias2, boff2);
  offA_kernel<<<512, 256, 0, stream>>>(x, xTb, w2, boff2, om32);
  dcnB_kernel<<<2048, 256, 0, stream>>>((const unsigned short*)xTb, om32, Wm, bias2, outp);
}